// Round 19
// baseline (68.984 us; speedup 1.0000x reference)
//
#include <hip/hip_runtime.h>
#include <string.h>

// Depthwise temporal FIR (FW=64, SAME pad low=31/high=32), weight-norm +
// positivity clamp + bias. out[t,c] = b[c] + sum_f relu(w[f,c]/||w||) x[t-31+f,c]
//
// Round-19 = Round-18 with the compile fix: __builtin_nontemporal_store
// can't take HIP float2 -> bit-cast to double (same 8B store).
// Structure: 2 CHANNELS PER LANE (float2) + v_pk_fma_f32 (2 FMA/instr, R14)
// + END-SCALING (relu(w/n)x == max(w,0)x / n, n>0: accumulate unscaled,
// scale once at store -> no norm prepass). Acc-persistent tap-chunks of 16,
// R=16 outputs/thread. Live set ~90; FMA fraction ~70% of ~1.8k instr.
// pf[8] rolling prefetch. c-fast grid (R11), 2048 blocks, no occupancy attr.

#define T_DIM 4096
#define C2    2048        // row stride in float2 (C_DIM/2)
#define PAD_L 31
#define R     16          // time outputs per thread
#define CH    16          // taps per chunk
#define NCH   4

__device__ __forceinline__ float2 pkfma(float2 a, float2 b, float2 c) {
    float2 d;
    asm("v_pk_fma_f32 %0, %1, %2, %3" : "=v"(d) : "v"(a), "v"(b), "v"(c));
    return d;
}

__device__ __forceinline__ void nt_store_f2(float2 v, float2* p) {
    double d;
    memcpy(&d, &v, 8);                      // bit-cast, folds to a reg move
    __builtin_nontemporal_store(d, (double*)p);
}

template <bool GUARD>
__device__ __forceinline__ void fir_body(const float2* __restrict__ x2,
                                         const float2* __restrict__ w2,
                                         const float2* __restrict__ b2,
                                         float2* __restrict__ out2,
                                         int cq, int t0) {
    const float2* __restrict__ xp2 = x2 + cq;      // channel-pair column base
    const float2* __restrict__ wp2 = w2 + cq;

    float2 acc[R];
#pragma unroll
    for (int r = 0; r < R; ++r) acc[r] = make_float2(0.f, 0.f);
    float2 ssv = make_float2(0.f, 0.f);            // sum of w^2 (per channel)

#define LOADX2(m) ((!GUARD || ((unsigned)(m) < (unsigned)T_DIM))              \
                       ? xp2[(long long)(m) * C2] : make_float2(0.f, 0.f))

    // one streamed x pair; j compile-time -> static wf/acc/pf indices
#define XSTEP(j)                                                              \
    {                                                                         \
        const float2 xv = pf[(j) & 7];                                        \
        if ((j) <= 2 * CH - 2 - 8)               /* refill while in range */  \
            pf[(j) & 7] = LOADX2(xb + (j) + 8);                               \
        _Pragma("unroll")                                                     \
        for (int r = 0; r < R; ++r)                                           \
            if ((j) - r >= 0 && (j) - r < CH)    /* folds at compile time */  \
                acc[r] = pkfma(wf[(j) - r], xv, acc[r]);                      \
    }

    // ---- 4 tap-chunks; acc[] and ssv persist, everything else streams ----
#pragma unroll 1
    for (int q = 0; q < NCH; ++q) {
        // chunk weights: unscaled positive part; ssv accumulates w^2
        float2 wf[CH];
#pragma unroll
        for (int j = 0; j < CH; ++j) {
            const float2 wv = wp2[(q * CH + j) * C2];
            ssv = pkfma(wv, wv, ssv);
            wf[j] = make_float2(fmaxf(wv.x, 0.f), fmaxf(wv.y, 0.f));
        }

        // x window for this chunk: x[xb .. xb+30]
        const int xb = t0 - PAD_L + q * CH;
        float2 pf[8];
#pragma unroll
        for (int i = 0; i < 8; ++i) pf[i] = LOADX2(xb + i);

        XSTEP(0)  XSTEP(1)  XSTEP(2)  XSTEP(3)  XSTEP(4)  XSTEP(5)
        XSTEP(6)  XSTEP(7)  XSTEP(8)  XSTEP(9)  XSTEP(10) XSTEP(11)
        XSTEP(12) XSTEP(13) XSTEP(14) XSTEP(15) XSTEP(16) XSTEP(17)
        XSTEP(18) XSTEP(19) XSTEP(20) XSTEP(21) XSTEP(22) XSTEP(23)
        XSTEP(24) XSTEP(25) XSTEP(26) XSTEP(27) XSTEP(28) XSTEP(29)
        XSTEP(30)
    }
#undef XSTEP

    // ---- finalize: out = acc / max(||w||,1e-8) + bias ----
    const float2 bv = b2[cq];
    const float ivx = 1.0f / fmaxf(sqrtf(ssv.x), 1e-8f);
    const float ivy = 1.0f / fmaxf(sqrtf(ssv.y), 1e-8f);

    float2* __restrict__ op = out2 + (long long)t0 * C2 + cq;
#pragma unroll
    for (int r = 0; r < R; ++r) {
        const float2 res = make_float2(fmaf(acc[r].x, ivx, bv.x),
                                       fmaf(acc[r].y, ivy, bv.y));
        nt_store_f2(res, op + (long long)r * C2);
    }
#undef LOADX2
}

__global__ __launch_bounds__(256)
void depthwise_fir_kernel(const float* __restrict__ x, const float* __restrict__ w,
                          const float* __restrict__ b, float* __restrict__ out) {
    const int cq = blockIdx.x * 256 + threadIdx.x;   // float2-channel; c-fastest
    const int t0 = blockIdx.y * R;
    // guard only where the 47-row window leaves [0,T): t0-31<0 or t0+47>4095
    if (blockIdx.y < 2 || blockIdx.y >= gridDim.y - 2)
        fir_body<true>((const float2*)x, (const float2*)w, (const float2*)b,
                       (float2*)out, cq, t0);
    else
        fir_body<false>((const float2*)x, (const float2*)w, (const float2*)b,
                        (float2*)out, cq, t0);
}

extern "C" void kernel_launch(void* const* d_in, const int* in_sizes, int n_in,
                              void* d_out, int out_size, void* d_ws, size_t ws_size,
                              hipStream_t stream) {
    const float* x = (const float*)d_in[0];   // [T, C]
    const float* w = (const float*)d_in[1];   // [FW, C]
    const float* b = (const float*)d_in[2];   // [C]
    float* out = (float*)d_out;               // [T, C]

    dim3 grid(C2 / 256, T_DIM / R);           // 8 x 256 = 2048 blocks = 8/CU
    dim3 block(256);
    hipLaunchKernelGGL(depthwise_fir_kernel, grid, block, 0, stream, x, w, b, out);
}

// Round 20
// 57.019 us; speedup vs baseline: 1.2099x; 1.2099x over previous
//
#include <hip/hip_runtime.h>

// Depthwise temporal FIR (FW=64, SAME pad low=31/high=32), weight-norm +
// positivity clamp + bias. out[t,c] = b[c] + sum_f relu(w[f,c]/||w||) x[t-31+f,c]
//
// Round-20: R10's 4-way tap-split skeleton (grp = lane>>4 owns taps
// 16g..16g+15 of 16 channels; all groups compute the SAME output row each
// step; 2-level shfl_xor butterfly sums groups; rotating group stores every
// 4th step) with the two flaws fixed:
//  (1) live set cut to ~44 (wf16+xbuf16+pf[4]+res/addr) -- the allocator
//      empirically targets ~44 VGPRs; at live<=44 parking movs vanish
//      (R10 was live 58 @ VGPR 40 -> ~2.4x VALU inflation).
//  (2) c-blocks-fastest grid (R11: concurrent blocks tile whole rows ->
//      FETCH 90 -> ~50 MB).
// pf[4] rolling prefetch, refill folded into each step: 4-step load->use
// distance x ~4 resident waves covers HBM latency. No LDS, no barriers.

#define T_DIM 4096
#define C_DIM 4096
#define PAD_L 31
#define TPG   16      // taps per group (lane)
#define KTILE 128     // output rows per block
#define CB    64      // channels per block (4 waves x 16)
#define NPER  (KTILE / 16)

template <bool GUARD>
__device__ __forceinline__ void fir_body(const float* __restrict__ x,
                                         const float* __restrict__ w,
                                         const float* __restrict__ bia,
                                         float* __restrict__ out,
                                         int c, int grp, int t0) {
    const float* __restrict__ xp = x + c;                 // channel column base

    // ---- weights of this lane's tap group; weight-norm across 4 groups ----
    float wf[TPG];
    float ss = 0.0f;
#pragma unroll
    for (int j = 0; j < TPG; ++j) {
        wf[j] = w[(grp * TPG + j) * C_DIM + c];
        ss = fmaf(wf[j], wf[j], ss);
    }
    ss += __shfl_xor(ss, 16);
    ss += __shfl_xor(ss, 32);                             // full 64-tap norm
    const float inv = 1.0f / fmaxf(sqrtf(ss), 1e-8f);
#pragma unroll
    for (int j = 0; j < TPG; ++j) wf[j] = fmaxf(wf[j] * inv, 0.0f);

    const float seed = (grp == 0) ? bia[c] : 0.0f;        // bias added once

    // group g's window base: output t0+s taps x[base+s .. base+s+15]
    const int base = t0 - PAD_L + TPG * grp;              // base % 16 == 1

#define LOADX(m) ((!GUARD || ((unsigned)(m) < (unsigned)T_DIM))               \
                      ? xp[(long long)(m) * C_DIM] : 0.0f)

    // ---- circular window: xbuf[m & 15] = x[m]; warm-up x[base..base+15] ----
    float xbuf[TPG];
#pragma unroll
    for (int i = 0; i < TPG; ++i) xbuf[(1 + i) & 15] = LOADX(base + i);

    // rolling 4-deep prefetch: pf[s & 3] = insert value of step s = x[base+16+s]
    float pf[4];
#pragma unroll
    for (int i = 0; i < 4; ++i) pf[i] = LOADX(base + 16 + i);

    float res = 0.0f;
    // this lane stores rows t0 + grp + 4q (all 64 lanes store together)
    float* __restrict__ opl = out + ((long long)t0 + grp) * C_DIM + c;

    // one step; kk compile-time (0..15), kb = 16p runtime. Window before the
    // step is x[base+kb+kk .. +15]; partial computed, then insert x[..+16],
    // then refill pf with the insert value of step kk+4.
#define FIR_STEP(kk)                                                          \
    {                                                                         \
        float a0 = seed, a1 = 0.0f;                                           \
        _Pragma("unroll")                                                     \
        for (int j = 0; j < TPG; j += 2) {                                    \
            a0 = fmaf(wf[j],     xbuf[(1 + (kk) + j) & 15], a0);              \
            a1 = fmaf(wf[j + 1], xbuf[(2 + (kk) + j) & 15], a1);              \
        }                                                                     \
        xbuf[(1 + (kk)) & 15] = pf[(kk) & 3];                                 \
        pf[(kk) & 3] = LOADX(base + 20 + kb + (kk));                          \
        float p1 = a0 + a1;                                                   \
        p1 += __shfl_xor(p1, 16);                                             \
        p1 += __shfl_xor(p1, 32);        /* full sum in all 4 group lanes */  \
        res = (grp == ((kk) & 3)) ? p1 : res;   /* 1 cndmask */               \
        if (((kk) & 3) == 3)             /* 64-lane store, rows kb+kk-3+grp */ \
            __builtin_nontemporal_store(res,                                  \
                opl + (long long)(kb + (kk) - 3) * C_DIM);                    \
    }

#pragma unroll 1
    for (int p = 0; p < NPER; ++p) {
        const int kb = p * 16;
        FIR_STEP(0)  FIR_STEP(1)  FIR_STEP(2)  FIR_STEP(3)
        FIR_STEP(4)  FIR_STEP(5)  FIR_STEP(6)  FIR_STEP(7)
        FIR_STEP(8)  FIR_STEP(9)  FIR_STEP(10) FIR_STEP(11)
        FIR_STEP(12) FIR_STEP(13) FIR_STEP(14) FIR_STEP(15)
    }

#undef FIR_STEP
#undef LOADX
}

__global__ __launch_bounds__(256) void depthwise_fir_kernel(
    const float* __restrict__ x, const float* __restrict__ w,
    const float* __restrict__ bia, float* __restrict__ out) {
    const int lane = threadIdx.x & 63;
    const int wave = threadIdx.x >> 6;
    const int grp  = lane >> 4;                  // tap group 0..3
    const int c    = blockIdx.x * CB + wave * 16 + (lane & 15);  // c-fastest
    const int t0   = blockIdx.y * KTILE;
    // zero-pad guard only at first/last time tile (block-uniform branch);
    // interior max address = t0 + 164 <= 4004 for t0 <= 3840 (in bounds)
    if (blockIdx.y == 0 || blockIdx.y == gridDim.y - 1)
        fir_body<true>(x, w, bia, out, c, grp, t0);
    else
        fir_body<false>(x, w, bia, out, c, grp, t0);
}

extern "C" void kernel_launch(void* const* d_in, const int* in_sizes, int n_in,
                              void* d_out, int out_size, void* d_ws, size_t ws_size,
                              hipStream_t stream) {
    const float* x = (const float*)d_in[0];   // [T, C]
    const float* w = (const float*)d_in[1];   // [FW, C]
    const float* b = (const float*)d_in[2];   // [C]
    float* out = (float*)d_out;               // [T, C]

    dim3 grid(C_DIM / CB, T_DIM / KTILE);     // 64 x 32 = 2048 blocks, c-fastest
    dim3 block(256);
    hipLaunchKernelGGL(depthwise_fir_kernel, grid, block, 0, stream, x, w, b, out);
}

// Round 21
// 43.988 us; speedup vs baseline: 1.5682x; 1.2962x over previous
//
#include <hip/hip_runtime.h>

// Depthwise temporal FIR (FW=64, SAME pad low=31/high=32), weight-norm +
// positivity clamp + bias. out[t,c] = b[c] + sum_f relu(w[f,c]/||w||) x[t-31+f,c]
//
// Round-21: the R15 winner (thread-per-channel, 64-slot circular register
// window, 8-deep rolling prefetch, no LDS/shuffles) with the grid-starvation
// fixed: KTILE 128 -> 64 gives 1024 blocks = 4 blocks/CU = 4 waves/SIMD
// (R15 ran 2/SIMD, occ 17%, VALUBusy 62% = TLP-starved). c-fastest grid
// (R11). END-SCALING: accumulate unscaled max(w,0)*x, apply 1/||w|| + bias
// at the store (saves the 64-mul scale pass; numerics validated R19).
// Straight-line 64-step body (one circular period), all indices static.

#define T_DIM 4096
#define C_DIM 4096
#define PAD_L 31
#define KTILE 64       // outputs per thread = one circular-buffer period

template <bool GUARD>
__device__ __forceinline__ void fir_body(const float* __restrict__ x,
                                         const float* __restrict__ w,
                                         const float* __restrict__ b,
                                         float* __restrict__ out,
                                         int c, int t0) {
    const float* __restrict__ xp = x + c;          // channel column base
    float* __restrict__ op = out + (long long)t0 * C_DIM + c;

    // ---- weights: positive part UNSCALED; norm applied at the store ----
    float wf[64];
    float ss = 0.0f;
#pragma unroll
    for (int f = 0; f < 64; ++f) {
        const float wv = w[f * C_DIM + c];
        ss = fmaf(wv, wv, ss);
        wf[f] = fmaxf(wv, 0.0f);
    }
    const float inv = 1.0f / fmaxf(sqrtf(ss), 1e-8f);
    const float bv = b[c];

    const int base = t0 - PAD_L;                   // t0 % 64 == 0 -> base%64 == 33

#define LOADX(m) ((!GUARD || ((unsigned)(m) < (unsigned)T_DIM))               \
                      ? xp[(long long)(m) * C_DIM] : 0.0f)

    // ---- circular window, invariant xbuf[m & 63] = x[m] ----
    float xbuf[64];
#pragma unroll
    for (int i = 0; i < 64; ++i) xbuf[(i + 33) & 63] = LOADX(base + i);

    // rolling 8-deep prefetch: pf[k & 7] = insert value of step k = x[base+64+k]
    float pf[8];
#pragma unroll
    for (int i = 0; i < 8; ++i) pf[i] = LOADX(base + 64 + i);

    // step k (compile-time 0..63): taps at slots (k+f+33)&63, insert, refill
#define FIR_STEP(k)                                                           \
    {                                                                         \
        float a0 = 0.0f, a1 = 0.0f, a2 = 0.0f, a3 = 0.0f;                     \
        _Pragma("unroll")                                                     \
        for (int f = 0; f < 64; f += 4) {                                     \
            a0 = fmaf(wf[f + 0], xbuf[((k) + f + 33) & 63], a0);              \
            a1 = fmaf(wf[f + 1], xbuf[((k) + f + 34) & 63], a1);              \
            a2 = fmaf(wf[f + 2], xbuf[((k) + f + 35) & 63], a2);              \
            a3 = fmaf(wf[f + 3], xbuf[((k) + f + 36) & 63], a3);              \
        }                                                                     \
        xbuf[((k) + 33) & 63] = pf[(k) & 7];                                  \
        if ((k) < KTILE - 8)              /* folds at compile time */         \
            pf[(k) & 7] = LOADX(base + 72 + (k));                             \
        __builtin_nontemporal_store(                                          \
            fmaf((a0 + a1) + (a2 + a3), inv, bv),                             \
            op + (long long)(k) * C_DIM);                                     \
    }

#define STEP8(b8) FIR_STEP(b8 + 0) FIR_STEP(b8 + 1) FIR_STEP(b8 + 2)          \
                  FIR_STEP(b8 + 3) FIR_STEP(b8 + 4) FIR_STEP(b8 + 5)          \
                  FIR_STEP(b8 + 6) FIR_STEP(b8 + 7)

    STEP8(0)  STEP8(8)  STEP8(16) STEP8(24)
    STEP8(32) STEP8(40) STEP8(48) STEP8(56)

#undef STEP8
#undef FIR_STEP
#undef LOADX
}

__global__ __launch_bounds__(256)
void depthwise_fir_kernel(const float* __restrict__ x, const float* __restrict__ w,
                          const float* __restrict__ b, float* __restrict__ out) {
    const int c  = blockIdx.x * 256 + threadIdx.x;   // c-blocks fastest (R11)
    const int t0 = blockIdx.y * KTILE;
    // zero-pad guard only at first/last time tile (block-uniform branch);
    // interior max address = t0 + 96 <= 4064, min = t0 - 31 >= 33: in bounds
    if (blockIdx.y == 0 || blockIdx.y == gridDim.y - 1)
        fir_body<true>(x, w, b, out, c, t0);
    else
        fir_body<false>(x, w, b, out, c, t0);
}

extern "C" void kernel_launch(void* const* d_in, const int* in_sizes, int n_in,
                              void* d_out, int out_size, void* d_ws, size_t ws_size,
                              hipStream_t stream) {
    const float* x = (const float*)d_in[0];   // [T, C]
    const float* w = (const float*)d_in[1];   // [FW, C]
    const float* b = (const float*)d_in[2];   // [C]
    float* out = (float*)d_out;               // [T, C]

    dim3 grid(C_DIM / 256, T_DIM / KTILE);    // 16 x 64 = 1024 blocks = 4/CU
    dim3 block(256);
    hipLaunchKernelGGL(depthwise_fir_kernel, grid, block, 0, stream, x, w, b, out);
}